// Round 8
// baseline (1959.414 us; speedup 1.0000x reference)
//
#include <hip/hip_runtime.h>
#include <hip/hip_bf16.h>
#include <math.h>

namespace {

constexpr int NU   = 50000;
constexpr int NI   = 30000;
constexpr int D    = 128;
constexpr int EUG  = 2000000;
constexpr int EAND = 1000000;
constexpr int EOR  = 1000000;
constexpr int NPASS = 3;     // dst-windowed fill passes
constexpr int HNB  = 8;      // histo blocks per (array,window) unit
constexpr int HW   = 16000;  // max histogram window (64 KB LDS)
constexpr int WSH  = 14;     // src-window shift (16384 ids/window)

typedef unsigned short ushort_t;

// ---- bf16 helpers ----
__device__ inline float bf_lo(unsigned v) { union { unsigned u; float f; } x{v << 16}; return x.f; }
__device__ inline float bf_hi(unsigned v) { union { unsigned u; float f; } x{v & 0xffff0000u}; return x.f; }
__device__ inline unsigned short f2bf(float f) {
  union { float f; unsigned u; } x{f};
  unsigned r = x.u + 0x7fffu + ((x.u >> 16) & 1u);
  return (unsigned short)(r >> 16);
}
__device__ inline unsigned pack2bf(float a, float b) {
  return (unsigned)f2bf(a) | ((unsigned)f2bf(b) << 16);
}

// ---------- fused: LDS-window histograms + bf16 cvt (unchanged, verified) ----------
struct HistoUnit { const int* idx; int* cnt; int E; int wbeg; int wend; };
struct HistoAll {
  HistoUnit u[22];
  int blkbase[23];
  int nunits;
  int nhisto;
  const float* a; unsigned* ah; long n2a;
  const float* b; unsigned* bh; long n2b;
};
__global__ __launch_bounds__(1024) void histo_cvt_k(HistoAll H) {
  __shared__ int h[HW];
  int gb = (int)blockIdx.x;
  if (gb >= H.nhisto) {
    long nb = (long)gridDim.x - H.nhisto;
    long total = H.n2a + H.n2b;
    for (long t = (long)(gb - H.nhisto) * 1024 + threadIdx.x; t < total; t += nb * 1024) {
      if (t < H.n2a) {
        float2 v = ((const float2*)H.a)[t];
        H.ah[t] = pack2bf(v.x, v.y);
      } else {
        long u = t - H.n2a;
        float2 v = ((const float2*)H.b)[u];
        H.bh[u] = pack2bf(v.x, v.y);
      }
    }
    return;
  }
  int unit = 0;
#pragma unroll
  for (int i = 1; i < 22; ++i) if (i < H.nunits && gb >= H.blkbase[i]) unit = i;
  HistoUnit U = H.u[unit];
  const int W = U.wend - U.wbeg;
  for (int i = threadIdx.x; i < W; i += 1024) h[i] = 0;
  __syncthreads();
  int chunk = gb - H.blkbase[unit];
  long b = (long)U.E * chunk / HNB;
  long e = (long)U.E * (chunk + 1) / HNB;
  const int* __restrict__ idx = U.idx;
  for (long j = b + threadIdx.x; j < e; j += 1024) {
    int v = idx[j] - U.wbeg;
    if ((unsigned)v < (unsigned)W) atomicAdd(&h[v], 1);
  }
  __syncthreads();
  for (int i = threadIdx.x; i < W; i += 1024) {
    int v = h[i];
    if (v) atomicAdd(&U.cnt[U.wbeg + i], v);
  }
}

// ---------- fused exclusive scans + rsqrt norms (unchanged, verified) ----------
struct ScanSeg { const int* cnt; int* off; int* cur; int n; };
struct ScanAll {
  ScanSeg s[6];
  const int* cnt_all; float* inv_all; int ncnt;
};
__global__ __launch_bounds__(1024) void exscan_norms_k(ScanAll S) {
  if (blockIdx.x >= 6) {
    int t = ((int)blockIdx.x - 6) * 1024 + threadIdx.x;
    if (t < S.ncnt) S.inv_all[t] = rsqrtf((float)max(S.cnt_all[t], 1));
    return;
  }
  ScanSeg sg = S.s[blockIdx.x];
  __shared__ int ts[1024];
  const int t = threadIdx.x;
  const int per = (sg.n + 1023) >> 10;
  const int b = min(t * per, sg.n);
  const int e = min(b + per, sg.n);
  int s = 0;
  for (int i = b; i < e; ++i) s += sg.cnt[i];
  ts[t] = s;
  __syncthreads();
  for (int d = 1; d < 1024; d <<= 1) {
    int v = (t >= d) ? ts[t - d] : 0;
    __syncthreads();
    ts[t] += v;
    __syncthreads();
  }
  if (t == 1023) sg.off[sg.n] = ts[1023];
  int run = (t == 0) ? 0 : ts[t - 1];
  for (int i = b; i < e; ++i) { sg.off[i] = run; sg.cur[i] = run; run += sg.cnt[i]; }
}

// ---------- windowed CSR fill: dst window [wbeg,wend) AND src window == srcwin ----------
struct FillWin {
  const int* dst[6];
  const int* src[6];
  int* cur[6];
  ushort_t* csrc[6];
  int iswt[6];          // weighted (UGu) segment flag
  float* cwt;
  const float* invS0;
  const float* wn0;
  const float* we0;
  int n[6];
  int wbeg[6];
  int wend[6];
  int blkbase[7];
  int nseg;
  int srcwin;
};
__global__ __launch_bounds__(256) void fill_win_k(FillWin F) {
  int seg = 0;
  for (int i = 1; i < 6; ++i) if (i < F.nseg && (int)blockIdx.x >= F.blkbase[i]) seg = i;
  int e = ((int)blockIdx.x - F.blkbase[seg]) * 256 + (int)threadIdx.x;
  if (e >= F.n[seg]) return;
  int dn = F.dst[seg][e];
  if (dn < F.wbeg[seg] || dn >= F.wend[seg]) return;
  int sn = F.src[seg][e];
  if ((sn >> WSH) != F.srcwin) return;
  int pos = atomicAdd(&F.cur[seg][dn], 1);
  F.csrc[seg][pos] = (ushort_t)sn;
  if (F.iswt[seg]) F.cwt[pos] = F.invS0[sn] * F.wn0[sn] * F.we0[e];
}

// ---------- cursor snapshot (window boundaries) ----------
struct SnapAll { const int* src[6]; int* dst[6]; int n[6]; int base[7]; int ns; };
__global__ __launch_bounds__(256) void snap_k(SnapAll S) {
  int t = (int)blockIdx.x * 256 + (int)threadIdx.x;
  int seg = 0;
  for (int i = 1; i < 6; ++i) if (i < S.ns && t >= S.base[i]) seg = i;
  int l = t - S.base[seg];
  if (l < S.n[seg]) S.dst[seg][l] = S.src[seg][l];
}

// ---------- multi-job windowed pull aggregation: one wave per dst row ----------
struct GJob {
  const unsigned* x; const int* roff; const ushort_t* csrc; const float* cwt;
  const float* invS; const float* invD;
  unsigned* out_h; float* out_f; float* pscr;     // pscr: fp32 partial scratch
  const int* bnd0; const int* bnd1; const int* bnd2;
  int nwin; int rbeg;
};
struct GJobs { GJob j[6]; int total; int gw; };

__global__ __launch_bounds__(256) void gather_multi_k(GJobs J) {
  int wid = ((int)blockIdx.x << 2) | ((int)threadIdx.x >> 6);
  if (wid >= J.total) return;
  GJob jb = J.j[0];
#pragma unroll
  for (int i = 1; i < 6; ++i) if (wid >= J.j[i].rbeg) jb = J.j[i];
  int row = wid - jb.rbeg;
  int lane = (int)threadIdx.x & 63;
  const int gw = J.gw;
  const int last = jb.nwin - 1;
  int lo = (gw == 0) ? jb.roff[row]
         : (gw == 1) ? jb.bnd0[row]
         : (gw == 2) ? jb.bnd1[row] : jb.bnd2[row];
  int hi = (gw == last) ? jb.roff[row + 1]
         : (gw == 0) ? jb.bnd0[row]
         : (gw == 1) ? jb.bnd1[row] : jb.bnd2[row];
  lo = __builtin_amdgcn_readfirstlane(lo);
  hi = __builtin_amdgcn_readfirstlane(hi);

  const unsigned* __restrict__ x = jb.x;
  const ushort_t* __restrict__ cs = jb.csrc;
  float ax = 0.f, ay = 0.f;
  int j = lo;
  if (jb.cwt) {
    const float* __restrict__ cw = jb.cwt;
    for (; j + 7 < hi; j += 8) {
      int s[8]; float w[8];
#pragma unroll
      for (int k = 0; k < 8; ++k) { s[k] = cs[j + k]; w[k] = cw[j + k]; }
#pragma unroll
      for (int k = 0; k < 8; ++k) {
        unsigned v = x[(size_t)s[k] * 64 + lane];
        ax = fmaf(w[k], bf_lo(v), ax); ay = fmaf(w[k], bf_hi(v), ay);
      }
    }
    for (; j < hi; ++j) {
      int s = cs[j]; float w = cw[j];
      unsigned v = x[(size_t)s * 64 + lane];
      ax = fmaf(w, bf_lo(v), ax); ay = fmaf(w, bf_hi(v), ay);
    }
  } else {
    const float* __restrict__ is = jb.invS;
    for (; j + 7 < hi; j += 8) {
      int s[8]; float w[8];
#pragma unroll
      for (int k = 0; k < 8; ++k) { s[k] = cs[j + k]; w[k] = is[s[k]]; }
#pragma unroll
      for (int k = 0; k < 8; ++k) {
        unsigned v = x[(size_t)s[k] * 64 + lane];
        ax = fmaf(w[k], bf_lo(v), ax); ay = fmaf(w[k], bf_hi(v), ay);
      }
    }
    for (; j < hi; ++j) {
      int s = cs[j]; float w = is[s];
      unsigned v = x[(size_t)s * 64 + lane];
      ax = fmaf(w, bf_lo(v), ax); ay = fmaf(w, bf_hi(v), ay);
    }
  }

  size_t oi = (size_t)row * 64 + lane;
  if (gw > 0) {
    if (jb.pscr) { float2 p = ((const float2*)jb.pscr)[oi]; ax += p.x; ay += p.y; }
    else if (jb.out_f) { float2 p = ((const float2*)jb.out_f)[oi]; ax += p.x; ay += p.y; }
    else { unsigned pv = jb.out_h[oi]; ax += bf_lo(pv); ay += bf_hi(pv); }
  }
  if (gw == last) {
    float si = jb.invD[row];
    ax *= si; ay *= si;
    if (jb.out_f) { float2 o; o.x = ax; o.y = ay; ((float2*)jb.out_f)[oi] = o; }
    else jb.out_h[oi] = pack2bf(ax, ay);
  } else {
    if (jb.pscr) { float2 o; o.x = ax; o.y = ay; ((float2*)jb.pscr)[oi] = o; }
    else if (jb.out_f) { float2 o; o.x = ax; o.y = ay; ((float2*)jb.out_f)[oi] = o; }
    else jb.out_h[oi] = pack2bf(ax, ay);
  }
}

// ---------- layer attention (unchanged, verified) ----------
struct AttnArgs {
  const unsigned* layer[7];
  float coef[7];
};

__device__ inline void osm_upd(float& m, float& den, float& num, float sc, float tv) {
  float nm = fmaxf(m, sc);
  float e0 = __expf(m - nm);
  float e1 = __expf(sc - nm);
  den = den * e0 + e1;
  num = num * e0 + tv * e1;
  m = nm;
}

template <int L>
__global__ __launch_bounds__(256) void attn_k(AttnArgs args,
    const float* __restrict__ W, const float* __restrict__ avec,
    float* __restrict__ out, float out_scale, int beta,
    const unsigned* __restrict__ extra, float escale, int n) {
  __shared__ float4 Ws4[2048];
  __shared__ float xs[32][132];
  const int tid = threadIdx.x;
  const int dt = tid & 15;
  const int grp = tid >> 4;
  const int half = blockIdx.y;
  const int base = blockIdx.x * 32;
  const float4* __restrict__ W4 = (const float4*)W;

  for (int i = tid; i < 2048; i += 256) {
    int k = i >> 4, d = i & 15;
    Ws4[i] = W4[(k << 5) + (half << 4) + d];
  }
  const float4 a4 = ((const float4*)avec)[(half << 4) + dt];
  const float am[4] = {a4.x, a4.y, a4.z, a4.w};

  float m[2][4], den[2][4], num[2][4];
#pragma unroll
  for (int g = 0; g < 2; ++g)
#pragma unroll
    for (int c = 0; c < 4; ++c) { m[g][c] = -3.0e38f; den[g][c] = 0.f; num[g][c] = 0.f; }

#pragma unroll
  for (int l = 0; l < L; ++l) {
    __syncthreads();
    const unsigned* __restrict__ Lh = args.layer[l];
    for (int i = tid; i < 2048; i += 256) {
      int r = i >> 6, c2 = i & 63;
      int node = base + r;
      unsigned v = (node < n) ? Lh[(size_t)node * 64 + c2] : 0u;
      xs[r][(c2 << 1)] = bf_lo(v);
      xs[r][(c2 << 1) + 1] = bf_hi(v);
    }
    __syncthreads();
    float s0[4] = {0.f, 0.f, 0.f, 0.f}, s1[4] = {0.f, 0.f, 0.f, 0.f};
#pragma unroll 4
    for (int k = 0; k < 128; ++k) {
      float4 w = Ws4[(k << 4) + dt];
      float x0 = xs[grp][k];
      float x1 = xs[grp + 16][k];
      s0[0] = fmaf(x0, w.x, s0[0]); s0[1] = fmaf(x0, w.y, s0[1]);
      s0[2] = fmaf(x0, w.z, s0[2]); s0[3] = fmaf(x0, w.w, s0[3]);
      s1[0] = fmaf(x1, w.x, s1[0]); s1[1] = fmaf(x1, w.y, s1[1]);
      s1[2] = fmaf(x1, w.z, s1[2]); s1[3] = fmaf(x1, w.w, s1[3]);
    }
    float c = args.coef[l];
    float4 t0 = *(const float4*)&xs[grp][(half << 6) + (dt << 2)];
    float4 t1 = *(const float4*)&xs[grp + 16][(half << 6) + (dt << 2)];
    const float tv0[4] = {t0.x, t0.y, t0.z, t0.w};
    const float tv1[4] = {t1.x, t1.y, t1.z, t1.w};
#pragma unroll
    for (int ch = 0; ch < 4; ++ch) {
      osm_upd(m[0][ch], den[0][ch], num[0][ch], c * s0[ch] * am[ch], c * tv0[ch]);
      osm_upd(m[1][ch], den[1][ch], num[1][ch], c * s1[ch] * am[ch], c * tv1[ch]);
    }
  }
#pragma unroll
  for (int g = 0; g < 2; ++g) {
    int node = base + grp + g * 16;
    if (node >= n) continue;
    float4 o;
    o.x = num[g][0] / den[g][0];
    o.y = num[g][1] / den[g][1];
    o.z = num[g][2] / den[g][2];
    o.w = num[g][3] / den[g][3];
    size_t oi = (size_t)node * 32 + (half << 4) + dt;
    float4* op = (float4*)out + oi;
    if (beta) {
      float4 pv = *op;
      float ex = 0.f, ey = 0.f, ez = 0.f, ew = 0.f;
      if (extra) {
        uint2 ev = ((const uint2*)extra)[oi];
        ex = bf_lo(ev.x); ey = bf_hi(ev.x); ez = bf_lo(ev.y); ew = bf_hi(ev.y);
      }
      o.x = pv.x + out_scale * o.x + escale * ex;
      o.y = pv.y + out_scale * o.y + escale * ey;
      o.z = pv.z + out_scale * o.z + escale * ez;
      o.w = pv.w + out_scale * o.w + escale * ew;
    } else {
      o.x *= out_scale; o.y *= out_scale; o.z *= out_scale; o.w *= out_scale;
    }
    *op = o;
  }
}

inline dim3 g1(long n) { return dim3((unsigned)((n + 255) / 256)); }

} // namespace

extern "C" void kernel_launch(void* const* d_in, const int* in_sizes, int n_in,
                              void* d_out, int out_size, void* d_ws, size_t ws_size,
                              hipStream_t stream) {
  const int* ug_u = (const int*)d_in[0];
  const int* ug_g = (const int*)d_in[1];
  const int* aS[3] = {(const int*)d_in[2], (const int*)d_in[4], (const int*)d_in[6]};
  const int* aD[3] = {(const int*)d_in[3], (const int*)d_in[5], (const int*)d_in[7]};
  const int* oS = (const int*)d_in[8];
  const int* oD = (const int*)d_in[9];
  const float* ue    = (const float*)d_in[10];
  const float* ie    = (const float*)d_in[11];
  const float* W_and = (const float*)d_in[12];
  const float* a_and = (const float*)d_in[13];
  const float* W_or  = (const float*)d_in[14];
  const float* a_or  = (const float*)d_in[15];
  const float* wedge = (const float*)d_in[16];
  const float* wnode = (const float*)d_in[17];

  // ---- workspace carve-up ----
  char* basep = (char*)d_ws;
  size_t boff_ = 0;
  auto alloc = [&](size_t bytes) -> void* {
    void* r = basep + boff_;
    boff_ += (bytes + 15) & ~(size_t)15;
    return r;
  };

  const int NCNT = NU + 9 * NI;
  int* cnt_all = (int*)alloc((size_t)NCNT * 4);
  float* inv_all = (float*)alloc((size_t)NCNT * 4);
  int* cU = cnt_all;
  int* cG = cU + NU;
  int* cAs[3], *cAd[3];
  { int* p = cG + NI;
    for (int i = 0; i < 3; ++i) { cAs[i] = p; p += NI; cAd[i] = p; p += NI; } }
  int* cOs = cAd[2] + NI;
  int* cOd = cOs + NI;
  float* invU = inv_all;
  float* invG = invU + NU;
  float* iAo[3], *iAi[3];
  { float* p = invG + NI;
    for (int i = 0; i < 3; ++i) { iAo[i] = p; p += NI; iAi[i] = p; p += NI; } }
  float* iOo = iAi[2] + NI;
  float* iOi = iOo + NI;

  int* oUGu = (int*)alloc((size_t)(NU + 1) * 4);
  int* oUGg = (int*)alloc((size_t)(NI + 1) * 4);
  int* oAnd[3]; for (int i = 0; i < 3; ++i) oAnd[i] = (int*)alloc((size_t)(NI + 1) * 4);
  int* oOr = (int*)alloc((size_t)(NI + 1) * 4);
  int* curUGu = (int*)alloc((size_t)(NU + 1) * 4);
  int* curUGg = (int*)alloc((size_t)(NI + 1) * 4);
  int* curAnd[3]; for (int i = 0; i < 3; ++i) curAnd[i] = (int*)alloc((size_t)(NI + 1) * 4);
  int* curOr = (int*)alloc((size_t)(NI + 1) * 4);

  // src-window boundary arrays
  int* bndU = (int*)alloc((size_t)NU * 4);
  int* bndG[3]; for (int i = 0; i < 3; ++i) bndG[i] = (int*)alloc((size_t)NI * 4);
  int* bndA[3]; for (int i = 0; i < 3; ++i) bndA[i] = (int*)alloc((size_t)NI * 4);
  int* bndO = (int*)alloc((size_t)NI * 4);

  ushort_t* sUGu = (ushort_t*)alloc((size_t)EUG * 2);
  float* wUGu = (float*)alloc((size_t)EUG * 4);
  ushort_t* sUGg = (ushort_t*)alloc((size_t)EUG * 2);
  ushort_t* sAnd[3]; for (int i = 0; i < 3; ++i) sAnd[i] = (ushort_t*)alloc((size_t)EAND * 2);
  ushort_t* sOr = (ushort_t*)alloc((size_t)EOR * 2);

  // bf16 tables (row = 64 uints = 256 B)
  unsigned* ieh = (unsigned*)alloc((size_t)NI * 64 * 4);
  unsigned* ueh = (unsigned*)alloc((size_t)NU * 64 * 4);
  unsigned* hu1 = (unsigned*)alloc((size_t)NU * 64 * 4);
  unsigned* hg1 = (unsigned*)alloc((size_t)NI * 64 * 4);
  unsigned* hg2 = (unsigned*)alloc((size_t)NI * 64 * 4);
  unsigned* ab[6]; for (int i = 0; i < 6; ++i) ab[i] = (unsigned*)alloc((size_t)NI * 64 * 4);
  unsigned* ob[3]; for (int i = 0; i < 3; ++i) ob[i] = (unsigned*)alloc((size_t)NI * 64 * 4);
  float* fscratch = (float*)alloc((size_t)NI * D * 4);   // fp32 partials for 4-window job

  float* out_hu = (float*)d_out;
  float* out_game = out_hu + (size_t)NU * D;

  // ---- zero counters ----
  hipMemsetAsync(cnt_all, 0, (size_t)NCNT * 4, stream);

  // ---- fused histograms + bf16 conversion ----
  HistoAll H{};
  {
    struct Arr { const int* idx; int* cnt; int E; int R; };
    Arr arrs[10] = {
      {ug_u, cU, EUG, NU}, {ug_g, cG, EUG, NI},
      {aS[0], cAs[0], EAND, NI}, {aD[0], cAd[0], EAND, NI},
      {aS[1], cAs[1], EAND, NI}, {aD[1], cAd[1], EAND, NI},
      {aS[2], cAs[2], EAND, NI}, {aD[2], cAd[2], EAND, NI},
      {oS, cOs, EOR, NI}, {oD, cOd, EOR, NI},
    };
    int nu = 0, bb = 0;
    for (int i = 0; i < 10; ++i) {
      int npass = (arrs[i].R + HW - 1) / HW;
      int win = (arrs[i].R + npass - 1) / npass;
      for (int p = 0; p < npass; ++p) {
        H.u[nu] = {arrs[i].idx, arrs[i].cnt, arrs[i].E,
                   p * win, min((p + 1) * win, arrs[i].R)};
        H.blkbase[nu] = bb;
        bb += HNB;
        ++nu;
      }
    }
    H.nunits = nu;
    H.blkbase[nu] = bb;
    H.nhisto = bb;
    H.a = ie; H.ah = ieh; H.n2a = (long)NI * 64;
    H.b = ue; H.bh = ueh; H.n2b = (long)NU * 64;
    int ncvt = 1360;
    histo_cvt_k<<<dim3(bb + ncvt), 1024, 0, stream>>>(H);
  }

  // ---- node-level scans (off + cur) + norms, fused ----
  ScanAll SA{};
  SA.s[0] = {cU, oUGu, curUGu, NU};
  SA.s[1] = {cG, oUGg, curUGg, NI};
  for (int i = 0; i < 3; ++i) SA.s[2 + i] = {cAd[i], oAnd[i], curAnd[i], NI};
  SA.s[5] = {cOd, oOr, curOr, NI};
  SA.cnt_all = cnt_all; SA.inv_all = inv_all; SA.ncnt = NCNT;
  exscan_norms_k<<<dim3(6 + (NCNT + 1023) / 1024), 1024, 0, stream>>>(SA);

  // ---- CSR fills: src-window outer, dst-window inner; snapshot boundaries ----
  // seg order: 0=UGu(dst u, src g, SW2) 1=UGg(dst g, src u, SW4) 2..4=AND(SW2) 5=OR(SW2)
  {
    const int* ds[6] = {ug_u, ug_g, aD[0], aD[1], aD[2], oD};
    const int* ss[6] = {ug_g, ug_u, aS[0], aS[1], aS[2], oS};
    int* cs[6] = {curUGu, curUGg, curAnd[0], curAnd[1], curAnd[2], curOr};
    ushort_t* os[6] = {sUGu, sUGg, sAnd[0], sAnd[1], sAnd[2], sOr};
    int ns[6] = {EUG, EUG, EAND, EAND, EAND, EOR};
    int nodecount[6] = {NU, NI, NI, NI, NI, NI};
    int segSW[6] = {2, 4, 2, 2, 2, 2};

    for (int w = 0; w < 4; ++w) {
      // active segs
      int act[6], na = 0;
      for (int i = 0; i < 6; ++i) if (w < segSW[i]) act[na++] = i;
      FillWin F{};
      int bb = 0;
      for (int k = 0; k < na; ++k) {
        int i = act[k];
        F.dst[k] = ds[i]; F.src[k] = ss[i]; F.cur[k] = cs[i]; F.csrc[k] = os[i];
        F.iswt[k] = (i == 0) ? 1 : 0; F.n[k] = ns[i];
        F.blkbase[k] = bb; bb += (ns[i] + 255) / 256;
      }
      F.blkbase[na] = bb; F.nseg = na; F.srcwin = w;
      F.cwt = wUGu; F.invS0 = invG; F.wn0 = wnode; F.we0 = wedge;
      for (int p = 0; p < NPASS; ++p) {
        for (int k = 0; k < na; ++k) {
          int i = act[k];
          int ww = (nodecount[i] + NPASS - 1) / NPASS;
          F.wbeg[k] = p * ww;
          F.wend[k] = min((p + 1) * ww, nodecount[i]);
        }
        fill_win_k<<<dim3(bb), 256, 0, stream>>>(F);
      }
      // snapshot boundaries after finishing src window w (not needed after last)
      if (w == 0) {
        SnapAll S{};
        const int* sc[6] = {curUGu, curUGg, curAnd[0], curAnd[1], curAnd[2], curOr};
        int* dd[6] = {bndU, bndG[0], bndA[0], bndA[1], bndA[2], bndO};
        int nn[6] = {NU, NI, NI, NI, NI, NI};
        int base = 0;
        for (int i = 0; i < 6; ++i) { S.src[i] = sc[i]; S.dst[i] = dd[i]; S.n[i] = nn[i]; S.base[i] = base; base += nn[i]; }
        S.base[6] = base; S.ns = 6;
        snap_k<<<g1(base), 256, 0, stream>>>(S);
      } else if (w < 3) {
        SnapAll S{};
        S.src[0] = curUGg; S.dst[0] = bndG[w]; S.n[0] = NI; S.base[0] = 0; S.base[1] = NI; S.ns = 1;
        snap_k<<<g1(NI), 256, 0, stream>>>(S);
      }
    }
  }

  // ---- windowed gathers ----
  struct JD { GJob g; int rows; };
  auto launch_stage = [&](JD* jobs, int nj) {
    int maxw = 0;
    for (int k = 0; k < nj; ++k) maxw = max(maxw, jobs[k].g.nwin);
    for (int gw = 0; gw < maxw; ++gw) {
      GJobs J{};
      int tot = 0, cnt = 0;
      for (int k = 0; k < nj; ++k) {
        if (gw >= jobs[k].g.nwin) continue;
        J.j[cnt] = jobs[k].g;
        J.j[cnt].rbeg = tot;
        tot += jobs[k].rows;
        ++cnt;
      }
      for (int k = cnt; k < 6; ++k) { J.j[k] = J.j[0]; J.j[k].rbeg = 0x7fffffff; }
      J.total = tot; J.gw = gw;
      gather_multi_k<<<dim3((tot + 3) / 4), 256, 0, stream>>>(J);
    }
  };

  // G1 (UGg first for per-table temporal locality)
  {
    JD js[6] = {
      {{ueh, oUGg, sUGg, nullptr, invU, invG, hg1, nullptr, fscratch, bndG[0], bndG[1], bndG[2], 4, 0}, NI},
      {{ieh, oUGu, sUGu, wUGu, nullptr, invU, hu1, nullptr, nullptr, bndU, nullptr, nullptr, 2, 0}, NU},
      {{ieh, oAnd[0], sAnd[0], nullptr, iAo[0], iAi[0], ab[0], nullptr, nullptr, bndA[0], nullptr, nullptr, 2, 0}, NI},
      {{ieh, oAnd[1], sAnd[1], nullptr, iAo[1], iAi[1], ab[1], nullptr, nullptr, bndA[1], nullptr, nullptr, 2, 0}, NI},
      {{ieh, oAnd[2], sAnd[2], nullptr, iAo[2], iAi[2], ab[2], nullptr, nullptr, bndA[2], nullptr, nullptr, 2, 0}, NI},
      {{ieh, oOr, sOr, nullptr, iOo, iOi, ob[0], nullptr, nullptr, bndO, nullptr, nullptr, 2, 0}, NI},
    };
    launch_stage(js, 6);
  }
  // G2
  {
    JD js[6] = {
      {{hu1, oUGg, sUGg, nullptr, invU, invG, hg2, nullptr, fscratch, bndG[0], bndG[1], bndG[2], 4, 0}, NI},
      {{hg1, oUGu, sUGu, wUGu, nullptr, invU, nullptr, out_hu, nullptr, bndU, nullptr, nullptr, 2, 0}, NU},
      {{ab[0], oAnd[0], sAnd[0], nullptr, iAo[0], iAi[0], ab[3], nullptr, nullptr, bndA[0], nullptr, nullptr, 2, 0}, NI},
      {{ab[1], oAnd[1], sAnd[1], nullptr, iAo[1], iAi[1], ab[4], nullptr, nullptr, bndA[1], nullptr, nullptr, 2, 0}, NI},
      {{ab[2], oAnd[2], sAnd[2], nullptr, iAo[2], iAi[2], ab[5], nullptr, nullptr, bndA[2], nullptr, nullptr, 2, 0}, NI},
      {{ob[0], oOr, sOr, nullptr, iOo, iOi, ob[1], nullptr, nullptr, bndO, nullptr, nullptr, 2, 0}, NI},
    };
    launch_stage(js, 6);
  }
  // G3
  {
    JD js[1] = {
      {{ob[1], oOr, sOr, nullptr, iOo, iOi, ob[2], nullptr, nullptr, bndO, nullptr, nullptr, 2, 0}, NI},
    };
    launch_stage(js, 1);
  }

  const float w_or = 80.0f / 82.0f;
  const float w_and = w_or / 80.0f;   // = 1/82
  const float w_self = w_and;

  // ---- layer attention ----
  AttnArgs aa{};
  aa.layer[0] = ieh;
  for (int i = 0; i < 6; ++i) aa.layer[1 + i] = ab[i];
  for (int i = 0; i < 7; ++i) aa.coef[i] = 1.0f;
  attn_k<7><<<dim3((NI + 31) / 32, 2), 256, 0, stream>>>(
      aa, W_and, a_and, out_game, w_and, 0, nullptr, 0.f, NI);

  AttnArgs ao{};
  ao.layer[0] = ieh; ao.layer[1] = ob[0]; ao.layer[2] = ob[1]; ao.layer[3] = ob[2];
  ao.coef[0] = 1.0f; ao.coef[1] = 0.6f; ao.coef[2] = 0.8f; ao.coef[3] = 1.0f;
  attn_k<4><<<dim3((NI + 31) / 32, 2), 256, 0, stream>>>(
      ao, W_or, a_or, out_game, w_or, 1, hg2, w_self, NI);
}

// Round 9
// 1853.161 us; speedup vs baseline: 1.0573x; 1.0573x over previous
//
#include <hip/hip_runtime.h>
#include <hip/hip_bf16.h>
#include <math.h>

namespace {

constexpr int NU   = 50000;
constexpr int NI   = 30000;
constexpr int D    = 128;
constexpr int EUG  = 2000000;
constexpr int EAND = 1000000;
constexpr int EOR  = 1000000;
constexpr int NPASS = 3;     // dst-windowed fill passes
constexpr int HNB  = 8;      // histo blocks per (array,window) unit
constexpr int HW   = 16000;  // max histogram window (64 KB LDS)

typedef unsigned short ushort_t;

// ---- bf16 helpers ----
__device__ inline float bf_lo(unsigned v) { union { unsigned u; float f; } x{v << 16}; return x.f; }
__device__ inline float bf_hi(unsigned v) { union { unsigned u; float f; } x{v & 0xffff0000u}; return x.f; }
__device__ inline unsigned short f2bf(float f) {
  union { float f; unsigned u; } x{f};
  unsigned r = x.u + 0x7fffu + ((x.u >> 16) & 1u);
  return (unsigned short)(r >> 16);
}
__device__ inline unsigned pack2bf(float a, float b) {
  return (unsigned)f2bf(a) | ((unsigned)f2bf(b) << 16);
}

// ---------- fused: LDS-window histograms + bf16 cvt (verified r6/r7) ----------
struct HistoUnit { const int* idx; int* cnt; int E; int wbeg; int wend; };
struct HistoAll {
  HistoUnit u[22];
  int blkbase[23];
  int nunits;
  int nhisto;
  const float* a; unsigned* ah; long n2a;
  const float* b; unsigned* bh; long n2b;
};
__global__ __launch_bounds__(1024) void histo_cvt_k(HistoAll H) {
  __shared__ int h[HW];
  int gb = (int)blockIdx.x;
  if (gb >= H.nhisto) {
    long nb = (long)gridDim.x - H.nhisto;
    long total = H.n2a + H.n2b;
    for (long t = (long)(gb - H.nhisto) * 1024 + threadIdx.x; t < total; t += nb * 1024) {
      if (t < H.n2a) {
        float2 v = ((const float2*)H.a)[t];
        H.ah[t] = pack2bf(v.x, v.y);
      } else {
        long u = t - H.n2a;
        float2 v = ((const float2*)H.b)[u];
        H.bh[u] = pack2bf(v.x, v.y);
      }
    }
    return;
  }
  int unit = 0;
#pragma unroll
  for (int i = 1; i < 22; ++i) if (i < H.nunits && gb >= H.blkbase[i]) unit = i;
  HistoUnit U = H.u[unit];
  const int W = U.wend - U.wbeg;
  for (int i = threadIdx.x; i < W; i += 1024) h[i] = 0;
  __syncthreads();
  int chunk = gb - H.blkbase[unit];
  long b = (long)U.E * chunk / HNB;
  long e = (long)U.E * (chunk + 1) / HNB;
  const int* __restrict__ idx = U.idx;
  for (long j = b + threadIdx.x; j < e; j += 1024) {
    int v = idx[j] - U.wbeg;
    if ((unsigned)v < (unsigned)W) atomicAdd(&h[v], 1);
  }
  __syncthreads();
  for (int i = threadIdx.x; i < W; i += 1024) {
    int v = h[i];
    if (v) atomicAdd(&U.cnt[U.wbeg + i], v);
  }
}

// ---------- fused exclusive scans + rsqrt norms (verified r6/r7) ----------
struct ScanSeg { const int* cnt; int* off; int* cur; int n; };
struct ScanAll {
  ScanSeg s[6];
  const int* cnt_all; float* inv_all; int ncnt;
};
__global__ __launch_bounds__(1024) void exscan_norms_k(ScanAll S) {
  if (blockIdx.x >= 6) {
    int t = ((int)blockIdx.x - 6) * 1024 + threadIdx.x;
    if (t < S.ncnt) S.inv_all[t] = rsqrtf((float)max(S.cnt_all[t], 1));
    return;
  }
  ScanSeg sg = S.s[blockIdx.x];
  __shared__ int ts[1024];
  const int t = threadIdx.x;
  const int per = (sg.n + 1023) >> 10;
  const int b = min(t * per, sg.n);
  const int e = min(b + per, sg.n);
  int s = 0;
  for (int i = b; i < e; ++i) s += sg.cnt[i];
  ts[t] = s;
  __syncthreads();
  for (int d = 1; d < 1024; d <<= 1) {
    int v = (t >= d) ? ts[t - d] : 0;
    __syncthreads();
    ts[t] += v;
    __syncthreads();
  }
  if (t == 1023) sg.off[sg.n] = ts[1023];
  int run = (t == 0) ? 0 : ts[t - 1];
  for (int i = b; i < e; ++i) { sg.off[i] = run; sg.cur[i] = run; run += sg.cnt[i]; }
}

// ---------- dst-windowed CSR fill, packing (bf16 weight | ushort src) ----------
struct FillWin {
  const int* dst[6];
  const int* src[6];
  int* cur[6];
  unsigned* meta[6];
  const float* invS[6];
  int iswt[6];          // UGu segment: weight *= wn[sn]*we[e]
  const float* wn0;
  const float* we0;
  int n[6];
  int wbeg[6];
  int wend[6];
  int blkbase[7];
};
__global__ __launch_bounds__(256) void fill_win_k(FillWin F) {
  int seg = 0;
#pragma unroll
  for (int i = 1; i < 6; ++i) if ((int)blockIdx.x >= F.blkbase[i]) seg = i;
  int e = ((int)blockIdx.x - F.blkbase[seg]) * 256 + (int)threadIdx.x;
  if (e >= F.n[seg]) return;
  int dn = F.dst[seg][e];
  if (dn < F.wbeg[seg] || dn >= F.wend[seg]) return;
  int sn = F.src[seg][e];
  float w = F.invS[seg][sn];
  if (F.iswt[seg]) w *= F.wn0[sn] * F.we0[e];
  int pos = atomicAdd(&F.cur[seg][dn], 1);
  F.meta[seg][pos] = ((unsigned)f2bf(w) << 16) | (unsigned)sn;
}

// ---------- multi-job pull aggregation: one 64-lane wave per dst row ----------
// Edge meta loaded 64-wide (coalesced), broadcast via __shfl: ~1 VMEM op/edge.
struct GJob {
  const unsigned* x; const int* roff; const unsigned* meta;
  const float* invD; unsigned* out_h; float* out_f; int rbeg;
};
struct GJobs { GJob j[6]; int total; };

__global__ __launch_bounds__(256) void gather_multi_k(GJobs J) {
  int wid = ((int)blockIdx.x << 2) | ((int)threadIdx.x >> 6);
  if (wid >= J.total) return;
  GJob jb = J.j[0];
#pragma unroll
  for (int i = 1; i < 6; ++i) if (wid >= J.j[i].rbeg) jb = J.j[i];
  int row = wid - jb.rbeg;
  int lane = (int)threadIdx.x & 63;
  int lo = __builtin_amdgcn_readfirstlane(jb.roff[row]);
  int hi = __builtin_amdgcn_readfirstlane(jb.roff[row + 1]);
  const unsigned* __restrict__ x = jb.x;
  const unsigned* __restrict__ mt = jb.meta;
  float ax = 0.f, ay = 0.f;

#define EDGE(kk)                                            \
  {                                                         \
    unsigned v = (unsigned)__shfl((int)mym, (kk));          \
    int s = (int)(v & 0xffffu);                             \
    float w = bf_hi(v);                                     \
    unsigned r = x[(size_t)s * 64 + lane];                  \
    ax = fmaf(w, bf_lo(r), ax);                             \
    ay = fmaf(w, bf_hi(r), ay);                             \
  }

  for (int p = lo; p < hi; p += 64) {
    unsigned mym = mt[p + lane];       // meta arrays have +64 slack
    int nk = hi - p;
    if (nk >= 64) {
#pragma unroll 8
      for (int k = 0; k < 64; ++k) EDGE(k)
    } else {
      for (int k = 0; k < nk; ++k) EDGE(k)
    }
  }
#undef EDGE

  float si = jb.invD[row];
  ax *= si; ay *= si;
  size_t oi = (size_t)row * 64 + lane;
  if (jb.out_f) {
    float2 o; o.x = ax; o.y = ay;
    ((float2*)jb.out_f)[oi] = o;
  } else {
    jb.out_h[oi] = pack2bf(ax, ay);
  }
}

// ---------- layer attention (verified since r2; bf16 layers) ----------
struct AttnArgs {
  const unsigned* layer[7];
  float coef[7];
};

__device__ inline void osm_upd(float& m, float& den, float& num, float sc, float tv) {
  float nm = fmaxf(m, sc);
  float e0 = __expf(m - nm);
  float e1 = __expf(sc - nm);
  den = den * e0 + e1;
  num = num * e0 + tv * e1;
  m = nm;
}

template <int L>
__global__ __launch_bounds__(256) void attn_k(AttnArgs args,
    const float* __restrict__ W, const float* __restrict__ avec,
    float* __restrict__ out, float out_scale, int beta,
    const unsigned* __restrict__ extra, float escale, int n) {
  __shared__ float4 Ws4[2048];
  __shared__ float xs[32][132];
  const int tid = threadIdx.x;
  const int dt = tid & 15;
  const int grp = tid >> 4;
  const int half = blockIdx.y;
  const int base = blockIdx.x * 32;
  const float4* __restrict__ W4 = (const float4*)W;

  for (int i = tid; i < 2048; i += 256) {
    int k = i >> 4, d = i & 15;
    Ws4[i] = W4[(k << 5) + (half << 4) + d];
  }
  const float4 a4 = ((const float4*)avec)[(half << 4) + dt];
  const float am[4] = {a4.x, a4.y, a4.z, a4.w};

  float m[2][4], den[2][4], num[2][4];
#pragma unroll
  for (int g = 0; g < 2; ++g)
#pragma unroll
    for (int c = 0; c < 4; ++c) { m[g][c] = -3.0e38f; den[g][c] = 0.f; num[g][c] = 0.f; }

#pragma unroll
  for (int l = 0; l < L; ++l) {
    __syncthreads();
    const unsigned* __restrict__ Lh = args.layer[l];
    for (int i = tid; i < 2048; i += 256) {
      int r = i >> 6, c2 = i & 63;
      int node = base + r;
      unsigned v = (node < n) ? Lh[(size_t)node * 64 + c2] : 0u;
      xs[r][(c2 << 1)] = bf_lo(v);
      xs[r][(c2 << 1) + 1] = bf_hi(v);
    }
    __syncthreads();
    float s0[4] = {0.f, 0.f, 0.f, 0.f}, s1[4] = {0.f, 0.f, 0.f, 0.f};
#pragma unroll 4
    for (int k = 0; k < 128; ++k) {
      float4 w = Ws4[(k << 4) + dt];
      float x0 = xs[grp][k];
      float x1 = xs[grp + 16][k];
      s0[0] = fmaf(x0, w.x, s0[0]); s0[1] = fmaf(x0, w.y, s0[1]);
      s0[2] = fmaf(x0, w.z, s0[2]); s0[3] = fmaf(x0, w.w, s0[3]);
      s1[0] = fmaf(x1, w.x, s1[0]); s1[1] = fmaf(x1, w.y, s1[1]);
      s1[2] = fmaf(x1, w.z, s1[2]); s1[3] = fmaf(x1, w.w, s1[3]);
    }
    float c = args.coef[l];
    float4 t0 = *(const float4*)&xs[grp][(half << 6) + (dt << 2)];
    float4 t1 = *(const float4*)&xs[grp + 16][(half << 6) + (dt << 2)];
    const float tv0[4] = {t0.x, t0.y, t0.z, t0.w};
    const float tv1[4] = {t1.x, t1.y, t1.z, t1.w};
#pragma unroll
    for (int ch = 0; ch < 4; ++ch) {
      osm_upd(m[0][ch], den[0][ch], num[0][ch], c * s0[ch] * am[ch], c * tv0[ch]);
      osm_upd(m[1][ch], den[1][ch], num[1][ch], c * s1[ch] * am[ch], c * tv1[ch]);
    }
  }
#pragma unroll
  for (int g = 0; g < 2; ++g) {
    int node = base + grp + g * 16;
    if (node >= n) continue;
    float4 o;
    o.x = num[g][0] / den[g][0];
    o.y = num[g][1] / den[g][1];
    o.z = num[g][2] / den[g][2];
    o.w = num[g][3] / den[g][3];
    size_t oi = (size_t)node * 32 + (half << 4) + dt;
    float4* op = (float4*)out + oi;
    if (beta) {
      float4 pv = *op;
      float ex = 0.f, ey = 0.f, ez = 0.f, ew = 0.f;
      if (extra) {
        uint2 ev = ((const uint2*)extra)[oi];
        ex = bf_lo(ev.x); ey = bf_hi(ev.x); ez = bf_lo(ev.y); ew = bf_hi(ev.y);
      }
      o.x = pv.x + out_scale * o.x + escale * ex;
      o.y = pv.y + out_scale * o.y + escale * ey;
      o.z = pv.z + out_scale * o.z + escale * ez;
      o.w = pv.w + out_scale * o.w + escale * ew;
    } else {
      o.x *= out_scale; o.y *= out_scale; o.z *= out_scale; o.w *= out_scale;
    }
    *op = o;
  }
}

inline dim3 g1(long n) { return dim3((unsigned)((n + 255) / 256)); }

} // namespace

extern "C" void kernel_launch(void* const* d_in, const int* in_sizes, int n_in,
                              void* d_out, int out_size, void* d_ws, size_t ws_size,
                              hipStream_t stream) {
  const int* ug_u = (const int*)d_in[0];
  const int* ug_g = (const int*)d_in[1];
  const int* aS[3] = {(const int*)d_in[2], (const int*)d_in[4], (const int*)d_in[6]};
  const int* aD[3] = {(const int*)d_in[3], (const int*)d_in[5], (const int*)d_in[7]};
  const int* oS = (const int*)d_in[8];
  const int* oD = (const int*)d_in[9];
  const float* ue    = (const float*)d_in[10];
  const float* ie    = (const float*)d_in[11];
  const float* W_and = (const float*)d_in[12];
  const float* a_and = (const float*)d_in[13];
  const float* W_or  = (const float*)d_in[14];
  const float* a_or  = (const float*)d_in[15];
  const float* wedge = (const float*)d_in[16];
  const float* wnode = (const float*)d_in[17];

  // ---- workspace carve-up ----
  char* basep = (char*)d_ws;
  size_t boff_ = 0;
  auto alloc = [&](size_t bytes) -> void* {
    void* r = basep + boff_;
    boff_ += (bytes + 15) & ~(size_t)15;
    return r;
  };

  const int NCNT = NU + 9 * NI;
  int* cnt_all = (int*)alloc((size_t)NCNT * 4);
  float* inv_all = (float*)alloc((size_t)NCNT * 4);
  int* cU = cnt_all;
  int* cG = cU + NU;
  int* cAs[3], *cAd[3];
  { int* p = cG + NI;
    for (int i = 0; i < 3; ++i) { cAs[i] = p; p += NI; cAd[i] = p; p += NI; } }
  int* cOs = cAd[2] + NI;
  int* cOd = cOs + NI;
  float* invU = inv_all;
  float* invG = invU + NU;
  float* iAo[3], *iAi[3];
  { float* p = invG + NI;
    for (int i = 0; i < 3; ++i) { iAo[i] = p; p += NI; iAi[i] = p; p += NI; } }
  float* iOo = iAi[2] + NI;
  float* iOi = iOo + NI;

  int* oUGu = (int*)alloc((size_t)(NU + 1) * 4);
  int* oUGg = (int*)alloc((size_t)(NI + 1) * 4);
  int* oAnd[3]; for (int i = 0; i < 3; ++i) oAnd[i] = (int*)alloc((size_t)(NI + 1) * 4);
  int* oOr = (int*)alloc((size_t)(NI + 1) * 4);
  int* curUGu = (int*)alloc((size_t)(NU + 1) * 4);
  int* curUGg = (int*)alloc((size_t)(NI + 1) * 4);
  int* curAnd[3]; for (int i = 0; i < 3; ++i) curAnd[i] = (int*)alloc((size_t)(NI + 1) * 4);
  int* curOr = (int*)alloc((size_t)(NI + 1) * 4);

  // packed edge meta (bf16 weight << 16 | src), +64 slack each for 64-wide loads
  unsigned* mUGu = (unsigned*)alloc((size_t)EUG * 4 + 256);
  unsigned* mUGg = (unsigned*)alloc((size_t)EUG * 4 + 256);
  unsigned* mAnd[3]; for (int i = 0; i < 3; ++i) mAnd[i] = (unsigned*)alloc((size_t)EAND * 4 + 256);
  unsigned* mOr = (unsigned*)alloc((size_t)EOR * 4 + 256);

  // bf16 tables (row = 64 uints = 256 B)
  unsigned* ieh = (unsigned*)alloc((size_t)NI * 64 * 4);
  unsigned* ueh = (unsigned*)alloc((size_t)NU * 64 * 4);
  unsigned* hu1 = (unsigned*)alloc((size_t)NU * 64 * 4);
  unsigned* hg1 = (unsigned*)alloc((size_t)NI * 64 * 4);
  unsigned* hg2 = (unsigned*)alloc((size_t)NI * 64 * 4);
  unsigned* ab[6]; for (int i = 0; i < 6; ++i) ab[i] = (unsigned*)alloc((size_t)NI * 64 * 4);
  unsigned* ob[3]; for (int i = 0; i < 3; ++i) ob[i] = (unsigned*)alloc((size_t)NI * 64 * 4);

  float* out_hu = (float*)d_out;
  float* out_game = out_hu + (size_t)NU * D;

  // ---- zero counters ----
  hipMemsetAsync(cnt_all, 0, (size_t)NCNT * 4, stream);

  // ---- fused histograms + bf16 conversion ----
  HistoAll H{};
  {
    struct Arr { const int* idx; int* cnt; int E; int R; };
    Arr arrs[10] = {
      {ug_u, cU, EUG, NU}, {ug_g, cG, EUG, NI},
      {aS[0], cAs[0], EAND, NI}, {aD[0], cAd[0], EAND, NI},
      {aS[1], cAs[1], EAND, NI}, {aD[1], cAd[1], EAND, NI},
      {aS[2], cAs[2], EAND, NI}, {aD[2], cAd[2], EAND, NI},
      {oS, cOs, EOR, NI}, {oD, cOd, EOR, NI},
    };
    int nu = 0, bb = 0;
    for (int i = 0; i < 10; ++i) {
      int npass = (arrs[i].R + HW - 1) / HW;
      int win = (arrs[i].R + npass - 1) / npass;
      for (int p = 0; p < npass; ++p) {
        H.u[nu] = {arrs[i].idx, arrs[i].cnt, arrs[i].E,
                   p * win, min((p + 1) * win, arrs[i].R)};
        H.blkbase[nu] = bb;
        bb += HNB;
        ++nu;
      }
    }
    H.nunits = nu;
    H.blkbase[nu] = bb;
    H.nhisto = bb;
    H.a = ie; H.ah = ieh; H.n2a = (long)NI * 64;
    H.b = ue; H.bh = ueh; H.n2b = (long)NU * 64;
    int ncvt = 1360;
    histo_cvt_k<<<dim3(bb + ncvt), 1024, 0, stream>>>(H);
  }

  // ---- node-level scans (off + cur) + norms, fused ----
  ScanAll SA{};
  SA.s[0] = {cU, oUGu, curUGu, NU};
  SA.s[1] = {cG, oUGg, curUGg, NI};
  for (int i = 0; i < 3; ++i) SA.s[2 + i] = {cAd[i], oAnd[i], curAnd[i], NI};
  SA.s[5] = {cOd, oOr, curOr, NI};
  SA.cnt_all = cnt_all; SA.inv_all = inv_all; SA.ncnt = NCNT;
  exscan_norms_k<<<dim3(6 + (NCNT + 1023) / 1024), 1024, 0, stream>>>(SA);

  // ---- dst-windowed CSR fills, packed meta ----
  FillWin F{};
  {
    const int* ds[6] = {ug_u, ug_g, aD[0], aD[1], aD[2], oD};
    const int* ss[6] = {ug_g, ug_u, aS[0], aS[1], aS[2], oS};
    int* cs[6] = {curUGu, curUGg, curAnd[0], curAnd[1], curAnd[2], curOr};
    unsigned* ms[6] = {mUGu, mUGg, mAnd[0], mAnd[1], mAnd[2], mOr};
    const float* iv[6] = {invG, invU, iAo[0], iAo[1], iAo[2], iOo};
    int ns[6] = {EUG, EUG, EAND, EAND, EAND, EOR};
    int bb = 0;
    for (int i = 0; i < 6; ++i) {
      F.dst[i] = ds[i]; F.src[i] = ss[i]; F.cur[i] = cs[i]; F.meta[i] = ms[i];
      F.invS[i] = iv[i]; F.iswt[i] = (i == 0) ? 1 : 0; F.n[i] = ns[i];
      F.blkbase[i] = bb; bb += (ns[i] + 255) / 256;
    }
    F.blkbase[6] = bb;
    F.wn0 = wnode; F.we0 = wedge;
  }
  const int nodecount[6] = {NU, NI, NI, NI, NI, NI};
  for (int p = 0; p < NPASS; ++p) {
    for (int i = 0; i < 6; ++i) {
      int w = (nodecount[i] + NPASS - 1) / NPASS;
      F.wbeg[i] = p * w;
      F.wend[i] = min((p + 1) * w, nodecount[i]);
    }
    fill_win_k<<<dim3(F.blkbase[6]), 256, 0, stream>>>(F);
  }

  // ---- gathers (multi-job, 6 jobs per launch) ----
  auto launch_bg = [&](GJob* jobs, const int* rows, int nj) {
    GJobs J{};
    int tot = 0;
    for (int k = 0; k < nj; ++k) {
      J.j[k] = jobs[k];
      J.j[k].rbeg = tot;
      tot += rows[k];
    }
    for (int k = nj; k < 6; ++k) { J.j[k] = J.j[0]; J.j[k].rbeg = 0x7fffffff; }
    J.total = tot;
    gather_multi_k<<<dim3((tot + 3) / 4), 256, 0, stream>>>(J);
  };

  // G1: hu1<-ieh (UGu), hg1<-ueh (UGg), ab0..2<-ieh (AND), ob0<-ieh (OR)
  {
    GJob js[6] = {
      {ieh, oUGu, mUGu, invU, hu1, nullptr, 0},
      {ueh, oUGg, mUGg, invG, hg1, nullptr, 0},
      {ieh, oAnd[0], mAnd[0], iAi[0], ab[0], nullptr, 0},
      {ieh, oAnd[1], mAnd[1], iAi[1], ab[1], nullptr, 0},
      {ieh, oAnd[2], mAnd[2], iAi[2], ab[2], nullptr, 0},
      {ieh, oOr, mOr, iOi, ob[0], nullptr, 0},
    };
    const int rows[6] = {NU, NI, NI, NI, NI, NI};
    launch_bg(js, rows, 6);
  }
  // G2: out_hu<-hg1 (fp32 out), hg2<-hu1, ab3..5<-ab0..2, ob1<-ob0
  {
    GJob js[6] = {
      {hg1, oUGu, mUGu, invU, nullptr, out_hu, 0},
      {hu1, oUGg, mUGg, invG, hg2, nullptr, 0},
      {ab[0], oAnd[0], mAnd[0], iAi[0], ab[3], nullptr, 0},
      {ab[1], oAnd[1], mAnd[1], iAi[1], ab[4], nullptr, 0},
      {ab[2], oAnd[2], mAnd[2], iAi[2], ab[5], nullptr, 0},
      {ob[0], oOr, mOr, iOi, ob[1], nullptr, 0},
    };
    const int rows[6] = {NU, NI, NI, NI, NI, NI};
    launch_bg(js, rows, 6);
  }
  // G3: ob2<-ob1
  {
    GJob js[1] = {{ob[1], oOr, mOr, iOi, ob[2], nullptr, 0}};
    const int rows[1] = {NI};
    launch_bg(js, rows, 1);
  }

  const float w_or = 80.0f / 82.0f;
  const float w_and = w_or / 80.0f;   // = 1/82
  const float w_self = w_and;

  // ---- layer attention ----
  AttnArgs aa{};
  aa.layer[0] = ieh;
  for (int i = 0; i < 6; ++i) aa.layer[1 + i] = ab[i];
  for (int i = 0; i < 7; ++i) aa.coef[i] = 1.0f;
  attn_k<7><<<dim3((NI + 31) / 32, 2), 256, 0, stream>>>(
      aa, W_and, a_and, out_game, w_and, 0, nullptr, 0.f, NI);

  AttnArgs ao{};
  ao.layer[0] = ieh; ao.layer[1] = ob[0]; ao.layer[2] = ob[1]; ao.layer[3] = ob[2];
  ao.coef[0] = 1.0f; ao.coef[1] = 0.6f; ao.coef[2] = 0.8f; ao.coef[3] = 1.0f;
  attn_k<4><<<dim3((NI + 31) / 32, 2), 256, 0, stream>>>(
      ao, W_or, a_or, out_game, w_or, 1, hg2, w_self, NI);
}